// Round 1
// baseline (2916.576 us; speedup 1.0000x reference)
//
#include <hip/hip_runtime.h>

#define NN 50000
#define NE 800000
#define DF 128
#define NG 64
#define NC 10

__device__ __forceinline__ void atomAddF(float* p, float v) {
  __hip_atomic_fetch_add(p, v, __ATOMIC_RELAXED, __HIP_MEMORY_SCOPE_AGENT);
}

// -------- edge scatter-add: agg[dst] += feat[src] --------
__global__ __launch_bounds__(256) void k_scatter(const float* __restrict__ feat,
                                                 float* __restrict__ agg,
                                                 const int* __restrict__ src,
                                                 const int* __restrict__ dst)
{
  const int f4 = (threadIdx.x & 31) * 4;   // float4 offset within a row
  const int es = threadIdx.x >> 5;         // 8 edges per block-iteration
  for (int e = blockIdx.x * 8 + es; e < NE; e += gridDim.x * 8) {
    const int s = src[e];
    const int t = dst[e];
    const float4 v = *reinterpret_cast<const float4*>(feat + (size_t)s * DF + f4);
    float* p = agg + (size_t)t * DF + f4;
    atomAddF(p + 0, v.x);
    atomAddF(p + 1, v.y);
    atomAddF(p + 2, v.z);
    atomAddF(p + 3, v.w);
  }
}

// -------- fused GEMM: out = relu((A1 [+ A2]) @ W + bias), in-place-safe --------
// M x 128 @ 128 x 128. Block tile: 128 rows. Thread tile 8x8.
// Cols owned per thread: {c0..c0+3} U {c0+64..c0+67}, c0=(tid&15)*4.
// Input tile stored transposed + XOR-swizzled: Is[k][r ^ (((k>>3)&7)<<2)].
__global__ __launch_bounds__(256, 2) void k_gemm(const float* __restrict__ A1,
                                                 const float* __restrict__ A2,
                                                 const float* __restrict__ W,
                                                 const float* __restrict__ bias,
                                                 float* __restrict__ out, int M)
{
  __shared__ float Ws[64][128];   // 32 KB
  __shared__ float Is[64][128];   // 32 KB (transposed, swizzled)
  const int tid  = threadIdx.x;
  const int row0 = blockIdx.x * 128;
  const int c0   = (tid & 15) * 4;
  const int r0   = (tid >> 4) * 4 * 2;   // 8 rows per thread, r0 in {0,8,...,120}

  float acc[8][8];
#pragma unroll
  for (int i = 0; i < 8; ++i)
#pragma unroll
    for (int j = 0; j < 8; ++j) acc[i][j] = 0.f;

  for (int kt = 0; kt < 128; kt += 64) {
    __syncthreads();
    // stage W half-tile: rows kt..kt+63, all 128 cols
#pragma unroll
    for (int i = 0; i < 8; ++i) {
      int flat = i * 256 + tid;          // float4 index, 2048 total
      int kl = flat >> 5;
      int cc = (flat & 31) * 4;
      *reinterpret_cast<float4*>(&Ws[kl][cc]) =
          *reinterpret_cast<const float4*>(&W[(size_t)(kt + kl) * 128 + cc]);
    }
    // stage input half-tile, transposed + swizzled
#pragma unroll
    for (int i = 0; i < 8; ++i) {
      int flat = i * 256 + tid;          // 2048 float4s: 128 rows x 16
      int r  = flat >> 4;
      int kk = flat & 15;
      float4 v;
      const int grow = row0 + r;
      if (grow < M) {
        v = *reinterpret_cast<const float4*>(&A1[(size_t)grow * 128 + kt + kk * 4]);
        if (A2) {
          float4 w = *reinterpret_cast<const float4*>(&A2[(size_t)grow * 128 + kt + kk * 4]);
          v.x += w.x; v.y += w.y; v.z += w.z; v.w += w.w;
        }
      } else {
        v = make_float4(0.f, 0.f, 0.f, 0.f);
      }
      const int rs = r ^ (((kk >> 1) & 7) << 2);  // matches read swizzle: k>>3 == kk>>1
      const int kb = kk * 4;
      Is[kb + 0][rs] = v.x;
      Is[kb + 1][rs] = v.y;
      Is[kb + 2][rs] = v.z;
      Is[kb + 3][rs] = v.w;
    }
    __syncthreads();

#pragma unroll 4
    for (int k = 0; k < 64; ++k) {
      const int X  = ((k >> 3) & 7) << 2;
      const int b1 = r0 ^ X;
      const int b2 = b1 ^ 4;
      const float4 i1 = *reinterpret_cast<const float4*>(&Is[k][b1]); // rows r0..r0+3
      const float4 i2 = *reinterpret_cast<const float4*>(&Is[k][b2]); // rows r0+4..r0+7
      const float4 w1 = *reinterpret_cast<const float4*>(&Ws[k][c0]);
      const float4 w2 = *reinterpret_cast<const float4*>(&Ws[k][c0 + 64]);
      const float iv[8] = {i1.x, i1.y, i1.z, i1.w, i2.x, i2.y, i2.z, i2.w};
      const float wv[8] = {w1.x, w1.y, w1.z, w1.w, w2.x, w2.y, w2.z, w2.w};
#pragma unroll
      for (int r = 0; r < 8; ++r)
#pragma unroll
        for (int c = 0; c < 8; ++c)
          acc[r][c] = fmaf(iv[r], wv[c], acc[r][c]);
    }
  }

  // epilogue: bias + relu + store
  float bv[8];
#pragma unroll
  for (int c = 0; c < 4; ++c) { bv[c] = bias[c0 + c]; bv[c + 4] = bias[c0 + 64 + c]; }
#pragma unroll
  for (int r = 0; r < 8; ++r) {
    const int grow = row0 + r0 + r;
    if (grow < M) {
      float4 o1, o2;
      o1.x = fmaxf(acc[r][0] + bv[0], 0.f);
      o1.y = fmaxf(acc[r][1] + bv[1], 0.f);
      o1.z = fmaxf(acc[r][2] + bv[2], 0.f);
      o1.w = fmaxf(acc[r][3] + bv[3], 0.f);
      o2.x = fmaxf(acc[r][4] + bv[4], 0.f);
      o2.y = fmaxf(acc[r][5] + bv[5], 0.f);
      o2.z = fmaxf(acc[r][6] + bv[6], 0.f);
      o2.w = fmaxf(acc[r][7] + bv[7], 0.f);
      *reinterpret_cast<float4*>(&out[(size_t)grow * 128 + c0])      = o1;
      *reinterpret_cast<float4*>(&out[(size_t)grow * 128 + c0 + 64]) = o2;
    }
  }
}

// -------- segment-mean pooling (batch sorted): sums/cnts via few atomics --------
__global__ __launch_bounds__(128) void k_pool(const float* __restrict__ h,
                                              const int* __restrict__ batch,
                                              float* __restrict__ sums,
                                              int* __restrict__ cnts)
{
  const int d = threadIdx.x;
  const int start = blockIdx.x * 256;
  if (start >= NN) return;
  const int end = min(start + 256, NN);
  int g = batch[start];
  float acc = 0.f;
  int cnt = 0;
  for (int i = start; i < end; ++i) {
    const int gi = batch[i];
    if (gi != g) {
      atomAddF(&sums[g * DF + d], acc);
      if (d == 0) atomicAdd(&cnts[g], cnt);
      acc = 0.f; cnt = 0; g = gi;
    }
    acc += h[(size_t)i * DF + d];
    ++cnt;
  }
  atomAddF(&sums[g * DF + d], acc);
  if (d == 0) atomicAdd(&cnts[g], cnt);
}

// -------- head: mean -> @Wfc + bfc -> sigmoid --------
__global__ __launch_bounds__(256) void k_head(const float* __restrict__ sums,
                                              const int* __restrict__ cnts,
                                              const float* __restrict__ Wfc,
                                              const float* __restrict__ bfc,
                                              float* __restrict__ out)
{
  for (int o = threadIdx.x; o < NG * NC; o += 256) {
    const int g = o / NC, c = o % NC;
    const float inv = 1.f / fmaxf((float)cnts[g], 1.f);
    float z = bfc[c];
    for (int k = 0; k < DF; ++k)
      z = fmaf(sums[g * DF + k] * inv, Wfc[k * NC + c], z);
    out[o] = 1.f / (1.f + expf(-z));
  }
}

extern "C" void kernel_launch(void* const* d_in, const int* in_sizes, int n_in,
                              void* d_out, int out_size, void* d_ws, size_t ws_size,
                              hipStream_t stream)
{
  const float* x   = (const float*)d_in[0];
  const int*   ei  = (const int*)d_in[1];
  const int* batch = (const int*)d_in[2];
  const float* W1a = (const float*)d_in[3];
  const float* b1a = (const float*)d_in[4];
  const float* W1b = (const float*)d_in[5];
  const float* b1b = (const float*)d_in[6];
  const float* W2a = (const float*)d_in[7];
  const float* b2a = (const float*)d_in[8];
  const float* W2b = (const float*)d_in[9];
  const float* b2b = (const float*)d_in[10];
  const float* Wfc = (const float*)d_in[11];
  const float* bfc = (const float*)d_in[12];
  float* out = (float*)d_out;

  const int* src = ei;           // edge_index[0]
  const int* dst = ei + NE;      // edge_index[1]

  // workspace layout: A (25.6MB) | H (25.6MB) | sums (32KB) | cnts (256B)
  float* A    = (float*)d_ws;
  float* H    = A + (size_t)NN * DF;
  float* sums = H + (size_t)NN * DF;
  int*   cnts = (int*)(sums + NG * DF);

  const size_t NB = (size_t)NN * DF * sizeof(float);
  const int gemm_grid = (NN + 127) / 128;   // 391

  // ---- conv1 ----
  hipMemsetAsync(A, 0, NB, stream);
  k_scatter<<<8192, 256, 0, stream>>>(x, A, src, dst);
  k_gemm<<<gemm_grid, 256, 0, stream>>>(x, A, W1a, b1a, A, NN);        // A = relu((x+agg)W1a+b)
  k_gemm<<<gemm_grid, 256, 0, stream>>>(A, nullptr, W1b, b1b, A, NN);  // A = relu(A W1b+b) = h1

  // ---- conv2 ----
  hipMemsetAsync(H, 0, NB, stream);
  k_scatter<<<8192, 256, 0, stream>>>(A, H, src, dst);
  k_gemm<<<gemm_grid, 256, 0, stream>>>(A, H, W2a, b2a, H, NN);        // H = relu((h1+agg)W2a+b)
  k_gemm<<<gemm_grid, 256, 0, stream>>>(H, nullptr, W2b, b2b, H, NN);  // H = h2

  // ---- pool + head ----
  hipMemsetAsync(sums, 0, (size_t)NG * DF * sizeof(float) + NG * sizeof(int), stream);
  k_pool<<<(NN + 255) / 256, 128, 0, stream>>>(H, batch, sums, cnts);
  k_head<<<1, 256, 0, stream>>>(sums, cnts, Wfc, bfc, out);
}

// Round 2
// 522.743 us; speedup vs baseline: 5.5794x; 5.5794x over previous
//
#include <hip/hip_runtime.h>

#define NN 50000
#define NE 800000
#define DF 128
#define NG 64
#define NC 10

__device__ __forceinline__ void atomAddF(float* p, float v) {
  __hip_atomic_fetch_add(p, v, __ATOMIC_RELAXED, __HIP_MEMORY_SCOPE_AGENT);
}

// ======== CSR build ========
__global__ __launch_bounds__(256) void k_hist(const int* __restrict__ dst,
                                              int* __restrict__ deg)
{
  int e = blockIdx.x * 256 + threadIdx.x;
  if (e < NE) atomicAdd(&deg[dst[e]], 1);
}

// exclusive scan of deg[0..NN) -> rs[0..NN], copy into cur
__global__ __launch_bounds__(1024) void k_scan(const int* __restrict__ deg,
                                               int* __restrict__ rs,
                                               int* __restrict__ cur)
{
  __shared__ int part[1024];
  const int t = threadIdx.x;
  const int CH = (NN + 1023) / 1024;   // 49
  const int b = t * CH;
  const int e = min(b + CH, NN);
  int s = 0;
  for (int i = b; i < e; ++i) s += deg[i];
  part[t] = s;
  __syncthreads();
  // Hillis-Steele inclusive scan over 1024 partials
  for (int off = 1; off < 1024; off <<= 1) {
    int v = (t >= off) ? part[t - off] : 0;
    __syncthreads();
    part[t] += v;
    __syncthreads();
  }
  int excl = (t == 0) ? 0 : part[t - 1];
  for (int i = b; i < e; ++i) {
    rs[i] = excl;
    cur[i] = excl;
    excl += deg[i];
  }
  if (t == 1023) rs[NN] = excl;        // = NE
}

__global__ __launch_bounds__(256) void k_fill(const int* __restrict__ src,
                                              const int* __restrict__ dst,
                                              int* __restrict__ cur,
                                              int* __restrict__ es)
{
  int e = blockIdx.x * 256 + threadIdx.x;
  if (e < NE) {
    int p = atomicAdd(&cur[dst[e]], 1);
    es[p] = src[e];
  }
}

// ======== gather-aggregate: out[i] = feat[i] + sum_{j in CSR[i]} feat[src_j] ========
// one wave (64 lanes) per node, float2 per lane = full 512B row per instruction
__global__ __launch_bounds__(256) void k_gather(const float* __restrict__ feat,
                                                float* __restrict__ outp,
                                                const int* __restrict__ rs,
                                                const int* __restrict__ es)
{
  const int wid  = (blockIdx.x * 256 + threadIdx.x) >> 6;   // node id
  const int lane = threadIdx.x & 63;
  if (wid >= NN) return;
  const int beg = rs[wid];
  const int end = rs[wid + 1];
  const int off = lane * 2;

  float2 acc = *reinterpret_cast<const float2*>(feat + (size_t)wid * DF + off);
  int j = beg;
  for (; j + 1 < end; j += 2) {
    const int s0 = es[j];
    const int s1 = es[j + 1];
    const float2 v0 = *reinterpret_cast<const float2*>(feat + (size_t)s0 * DF + off);
    const float2 v1 = *reinterpret_cast<const float2*>(feat + (size_t)s1 * DF + off);
    acc.x += v0.x + v1.x;
    acc.y += v0.y + v1.y;
  }
  if (j < end) {
    const int s0 = es[j];
    const float2 v0 = *reinterpret_cast<const float2*>(feat + (size_t)s0 * DF + off);
    acc.x += v0.x;
    acc.y += v0.y;
  }
  *reinterpret_cast<float2*>(outp + (size_t)wid * DF + off) = acc;
}

// ======== fused GEMM: out = relu(A @ W + bias), in-place-safe (row-block-owned) ========
__global__ __launch_bounds__(256, 2) void k_gemm(const float* __restrict__ A1,
                                                 const float* __restrict__ W,
                                                 const float* __restrict__ bias,
                                                 float* __restrict__ out, int M)
{
  __shared__ float Ws[64][128];   // 32 KB
  __shared__ float Is[64][128];   // 32 KB (transposed, swizzled)
  const int tid  = threadIdx.x;
  const int row0 = blockIdx.x * 128;
  const int c0   = (tid & 15) * 4;
  const int r0   = (tid >> 4) * 8;

  float acc[8][8];
#pragma unroll
  for (int i = 0; i < 8; ++i)
#pragma unroll
    for (int j = 0; j < 8; ++j) acc[i][j] = 0.f;

  for (int kt = 0; kt < 128; kt += 64) {
    __syncthreads();
#pragma unroll
    for (int i = 0; i < 8; ++i) {
      int flat = i * 256 + tid;
      int kl = flat >> 5;
      int cc = (flat & 31) * 4;
      *reinterpret_cast<float4*>(&Ws[kl][cc]) =
          *reinterpret_cast<const float4*>(&W[(size_t)(kt + kl) * 128 + cc]);
    }
#pragma unroll
    for (int i = 0; i < 8; ++i) {
      int flat = i * 256 + tid;
      int r  = flat >> 4;
      int kk = flat & 15;
      float4 v;
      const int grow = row0 + r;
      if (grow < M) {
        v = *reinterpret_cast<const float4*>(&A1[(size_t)grow * 128 + kt + kk * 4]);
      } else {
        v = make_float4(0.f, 0.f, 0.f, 0.f);
      }
      const int rs_ = r ^ (((kk >> 1) & 7) << 2);
      const int kb = kk * 4;
      Is[kb + 0][rs_] = v.x;
      Is[kb + 1][rs_] = v.y;
      Is[kb + 2][rs_] = v.z;
      Is[kb + 3][rs_] = v.w;
    }
    __syncthreads();

#pragma unroll 4
    for (int k = 0; k < 64; ++k) {
      const int X  = ((k >> 3) & 7) << 2;
      const int b1 = r0 ^ X;
      const int b2 = b1 ^ 4;
      const float4 i1 = *reinterpret_cast<const float4*>(&Is[k][b1]);
      const float4 i2 = *reinterpret_cast<const float4*>(&Is[k][b2]);
      const float4 w1 = *reinterpret_cast<const float4*>(&Ws[k][c0]);
      const float4 w2 = *reinterpret_cast<const float4*>(&Ws[k][c0 + 64]);
      const float iv[8] = {i1.x, i1.y, i1.z, i1.w, i2.x, i2.y, i2.z, i2.w};
      const float wv[8] = {w1.x, w1.y, w1.z, w1.w, w2.x, w2.y, w2.z, w2.w};
#pragma unroll
      for (int r = 0; r < 8; ++r)
#pragma unroll
        for (int c = 0; c < 8; ++c)
          acc[r][c] = fmaf(iv[r], wv[c], acc[r][c]);
    }
  }

  float bv[8];
#pragma unroll
  for (int c = 0; c < 4; ++c) { bv[c] = bias[c0 + c]; bv[c + 4] = bias[c0 + 64 + c]; }
#pragma unroll
  for (int r = 0; r < 8; ++r) {
    const int grow = row0 + r0 + r;
    if (grow < M) {
      float4 o1, o2;
      o1.x = fmaxf(acc[r][0] + bv[0], 0.f);
      o1.y = fmaxf(acc[r][1] + bv[1], 0.f);
      o1.z = fmaxf(acc[r][2] + bv[2], 0.f);
      o1.w = fmaxf(acc[r][3] + bv[3], 0.f);
      o2.x = fmaxf(acc[r][4] + bv[4], 0.f);
      o2.y = fmaxf(acc[r][5] + bv[5], 0.f);
      o2.z = fmaxf(acc[r][6] + bv[6], 0.f);
      o2.w = fmaxf(acc[r][7] + bv[7], 0.f);
      *reinterpret_cast<float4*>(&out[(size_t)grow * 128 + c0])      = o1;
      *reinterpret_cast<float4*>(&out[(size_t)grow * 128 + c0 + 64]) = o2;
    }
  }
}

// ======== segment-mean pooling (batch sorted) ========
__global__ __launch_bounds__(128) void k_pool(const float* __restrict__ h,
                                              const int* __restrict__ batch,
                                              float* __restrict__ sums,
                                              int* __restrict__ cnts)
{
  const int d = threadIdx.x;
  const int start = blockIdx.x * 256;
  if (start >= NN) return;
  const int end = min(start + 256, NN);
  int g = batch[start];
  float acc = 0.f;
  int cnt = 0;
  for (int i = start; i < end; ++i) {
    const int gi = batch[i];
    if (gi != g) {
      atomAddF(&sums[g * DF + d], acc);
      if (d == 0) atomicAdd(&cnts[g], cnt);
      acc = 0.f; cnt = 0; g = gi;
    }
    acc += h[(size_t)i * DF + d];
    ++cnt;
  }
  atomAddF(&sums[g * DF + d], acc);
  if (d == 0) atomicAdd(&cnts[g], cnt);
}

// ======== head: mean -> @Wfc + bfc -> sigmoid ========
__global__ __launch_bounds__(256) void k_head(const float* __restrict__ sums,
                                              const int* __restrict__ cnts,
                                              const float* __restrict__ Wfc,
                                              const float* __restrict__ bfc,
                                              float* __restrict__ out)
{
  for (int o = threadIdx.x; o < NG * NC; o += 256) {
    const int g = o / NC, c = o % NC;
    const float inv = 1.f / fmaxf((float)cnts[g], 1.f);
    float z = bfc[c];
    for (int k = 0; k < DF; ++k)
      z = fmaf(sums[g * DF + k] * inv, Wfc[k * NC + c], z);
    out[o] = 1.f / (1.f + expf(-z));
  }
}

extern "C" void kernel_launch(void* const* d_in, const int* in_sizes, int n_in,
                              void* d_out, int out_size, void* d_ws, size_t ws_size,
                              hipStream_t stream)
{
  const float* x   = (const float*)d_in[0];
  const int*   ei  = (const int*)d_in[1];
  const int* batch = (const int*)d_in[2];
  const float* W1a = (const float*)d_in[3];
  const float* b1a = (const float*)d_in[4];
  const float* W1b = (const float*)d_in[5];
  const float* b1b = (const float*)d_in[6];
  const float* W2a = (const float*)d_in[7];
  const float* b2a = (const float*)d_in[8];
  const float* W2b = (const float*)d_in[9];
  const float* b2b = (const float*)d_in[10];
  const float* Wfc = (const float*)d_in[11];
  const float* bfc = (const float*)d_in[12];
  float* out = (float*)d_out;

  const int* src = ei;           // edge_index[0]
  const int* dst = ei + NE;      // edge_index[1]

  // ws layout: A | H | sums | cnts | deg | rs | cur | es   (~55 MB total)
  float* A    = (float*)d_ws;
  float* H    = A + (size_t)NN * DF;
  float* sums = H + (size_t)NN * DF;
  int*   cnts = (int*)(sums + NG * DF);
  int*   deg  = cnts + 64;
  int*   rs   = deg + NN;
  int*   cur  = rs + (NN + 1);
  int*   es   = cur + NN;

  const int gemm_grid   = (NN + 127) / 128;   // 391
  const int gather_grid = (NN * 64 + 255) / 256;  // 12500
  const int edge_grid   = (NE + 255) / 256;   // 3125

  // ---- CSR build (per call; edge list is constant input) ----
  hipMemsetAsync(deg, 0, NN * sizeof(int), stream);
  k_hist<<<edge_grid, 256, 0, stream>>>(dst, deg);
  k_scan<<<1, 1024, 0, stream>>>(deg, rs, cur);
  k_fill<<<edge_grid, 256, 0, stream>>>(src, dst, cur, es);

  // ---- conv1 ----
  k_gather<<<gather_grid, 256, 0, stream>>>(x, A, rs, es);          // A = x + agg(x)
  k_gemm<<<gemm_grid, 256, 0, stream>>>(A, W1a, b1a, A, NN);        // A = relu(A W1a+b)
  k_gemm<<<gemm_grid, 256, 0, stream>>>(A, W1b, b1b, A, NN);        // A = h1

  // ---- conv2 ----
  k_gather<<<gather_grid, 256, 0, stream>>>(A, H, rs, es);          // H = h1 + agg(h1)
  k_gemm<<<gemm_grid, 256, 0, stream>>>(H, W2a, b2a, H, NN);        // H = relu(H W2a+b)
  k_gemm<<<gemm_grid, 256, 0, stream>>>(H, W2b, b2b, H, NN);        // H = h2

  // ---- pool + head ----
  hipMemsetAsync(sums, 0, (size_t)NG * DF * sizeof(float) + NG * sizeof(int), stream);
  k_pool<<<(NN + 255) / 256, 128, 0, stream>>>(H, batch, sums, cnts);
  k_head<<<1, 256, 0, stream>>>(sums, cnts, Wfc, bfc, out);
}

// Round 3
// 413.143 us; speedup vs baseline: 7.0595x; 1.2653x over previous
//
#include <hip/hip_runtime.h>

#define NN 50000
#define NE 800000
#define DF 128
#define NG 64
#define NC 10
#define SCAN_NB 49   // ceil(NN/1024)

__device__ __forceinline__ void atomAddF(float* p, float v) {
  __hip_atomic_fetch_add(p, v, __ATOMIC_RELAXED, __HIP_MEMORY_SCOPE_AGENT);
}
__device__ __forceinline__ float b2f(unsigned short u) {
  union { unsigned int i; float f; } v; v.i = (unsigned int)u << 16; return v.f;
}
__device__ __forceinline__ unsigned int f2b(float f) {   // RNE, finite inputs
  unsigned int i = __float_as_uint(f);
  return (i + 0x7fffu + ((i >> 16) & 1u)) >> 16;
}

// ======== cast x (fp32) -> xb (bf16) ========
__global__ __launch_bounds__(256) void k_cast(const float* __restrict__ x,
                                              unsigned short* __restrict__ xb)
{
  const int i = blockIdx.x * 256 + threadIdx.x;       // 4 floats per thread
  if (i * 4 >= NN * DF) return;
  const float4 v = reinterpret_cast<const float4*>(x)[i];
  uint2 o;
  o.x = f2b(v.x) | (f2b(v.y) << 16);
  o.y = f2b(v.z) | (f2b(v.w) << 16);
  reinterpret_cast<uint2*>(xb)[i] = o;
}

// ======== CSR build ========
__global__ __launch_bounds__(256) void k_hist(const int* __restrict__ dst,
                                              int* __restrict__ deg)
{
  int e = blockIdx.x * 256 + threadIdx.x;
  if (e < NE) atomicAdd(&deg[dst[e]], 1);
}

// local scan: block b handles deg[b*1024 .. +1024); writes local-exclusive to rs, block sum to part
__global__ __launch_bounds__(1024) void k_scan_a(const int* __restrict__ deg,
                                                 int* __restrict__ rs,
                                                 int* __restrict__ part)
{
  __shared__ int sm[1024];
  const int t = threadIdx.x;
  const int i = blockIdx.x * 1024 + t;
  const int d = (i < NN) ? deg[i] : 0;
  sm[t] = d;
  __syncthreads();
  for (int off = 1; off < 1024; off <<= 1) {
    int u = (t >= off) ? sm[t - off] : 0;
    __syncthreads();
    sm[t] += u;
    __syncthreads();
  }
  if (i < NN) rs[i] = sm[t] - d;           // local exclusive
  if (t == 1023) part[blockIdx.x] = sm[t]; // block total
}

// scan the 49 block partials (1 wave); part becomes exclusive offsets; writes rs[NN]
__global__ __launch_bounds__(64) void k_scan_b(int* __restrict__ part,
                                               int* __restrict__ rs)
{
  __shared__ int sm[64];
  const int t = threadIdx.x;
  const int v = (t < SCAN_NB) ? part[t] : 0;
  sm[t] = v;
  __syncthreads();
  for (int off = 1; off < 64; off <<= 1) {
    int u = (t >= off) ? sm[t - off] : 0;
    __syncthreads();
    sm[t] += u;
    __syncthreads();
  }
  part[t] = sm[t] - v;                     // exclusive offset
  if (t == 63) rs[NN] = sm[63];            // total = NE
}

// add block offsets, produce final rs and cur
__global__ __launch_bounds__(256) void k_scan_c(int* __restrict__ rs,
                                                const int* __restrict__ part,
                                                int* __restrict__ cur)
{
  const int i = blockIdx.x * 256 + threadIdx.x;
  if (i < NN) {
    const int v = rs[i] + part[i >> 10];
    rs[i] = v;
    cur[i] = v;
  }
}

__global__ __launch_bounds__(256) void k_fill(const int* __restrict__ src,
                                              const int* __restrict__ dst,
                                              int* __restrict__ cur,
                                              int* __restrict__ es)
{
  int e = blockIdx.x * 256 + threadIdx.x;
  if (e < NE) {
    int p = atomicAdd(&cur[dst[e]], 1);
    es[p] = src[e];
  }
}

// ======== gather-aggregate (bf16): out[i] = feat[i] + sum_j feat[es_j] ========
// one wave per node; lane holds 2 features (uint = 2 x bf16)
__global__ __launch_bounds__(256) void k_gather(const unsigned short* __restrict__ feat,
                                                unsigned short* __restrict__ outp,
                                                const int* __restrict__ rs,
                                                const int* __restrict__ es)
{
  const int wid  = (blockIdx.x * 256 + threadIdx.x) >> 6;
  const int lane = threadIdx.x & 63;
  if (wid >= NN) return;
  const int beg = rs[wid];
  const int end = rs[wid + 1];
  const int off = lane * 2;

  const unsigned int self = *reinterpret_cast<const unsigned int*>(feat + (size_t)wid * DF + off);
  float ax = b2f(self & 0xffff), ay = b2f(self >> 16);
  int j = beg;
  for (; j + 1 < end; j += 2) {
    const int s0 = es[j];
    const int s1 = es[j + 1];
    const unsigned int u0 = *reinterpret_cast<const unsigned int*>(feat + (size_t)s0 * DF + off);
    const unsigned int u1 = *reinterpret_cast<const unsigned int*>(feat + (size_t)s1 * DF + off);
    ax += b2f(u0 & 0xffff) + b2f(u1 & 0xffff);
    ay += b2f(u0 >> 16)    + b2f(u1 >> 16);
  }
  if (j < end) {
    const unsigned int u0 = *reinterpret_cast<const unsigned int*>(feat + (size_t)es[j] * DF + off);
    ax += b2f(u0 & 0xffff);
    ay += b2f(u0 >> 16);
  }
  const unsigned int o = f2b(ax) | (f2b(ay) << 16);
  *reinterpret_cast<unsigned int*>(outp + (size_t)wid * DF + off) = o;
}

// ======== fused GEMM: out(bf16) = relu(A(bf16) @ W(fp32) + bias), in-place-safe ========
__global__ __launch_bounds__(256, 2) void k_gemm(const unsigned short* __restrict__ Ab,
                                                 const float* __restrict__ W,
                                                 const float* __restrict__ bias,
                                                 unsigned short* __restrict__ outb, int M)
{
  __shared__ float Ws[64][128];   // 32 KB
  __shared__ float Is[64][128];   // 32 KB (transposed, swizzled)
  const int tid  = threadIdx.x;
  const int row0 = blockIdx.x * 128;
  const int c0   = (tid & 15) * 4;
  const int r0   = (tid >> 4) * 8;

  float acc[8][8];
#pragma unroll
  for (int i = 0; i < 8; ++i)
#pragma unroll
    for (int j = 0; j < 8; ++j) acc[i][j] = 0.f;

  for (int kt = 0; kt < 128; kt += 64) {
    __syncthreads();
#pragma unroll
    for (int i = 0; i < 8; ++i) {
      int flat = i * 256 + tid;
      int kl = flat >> 5;
      int cc = (flat & 31) * 4;
      *reinterpret_cast<float4*>(&Ws[kl][cc]) =
          *reinterpret_cast<const float4*>(&W[(size_t)(kt + kl) * 128 + cc]);
    }
#pragma unroll
    for (int i = 0; i < 8; ++i) {
      int flat = i * 256 + tid;
      int r  = flat >> 4;
      int kk = flat & 15;
      float4 v = make_float4(0.f, 0.f, 0.f, 0.f);
      const int grow = row0 + r;
      if (grow < M) {
        const ushort4 u = *reinterpret_cast<const ushort4*>(&Ab[(size_t)grow * 128 + kt + kk * 4]);
        v.x = b2f(u.x); v.y = b2f(u.y); v.z = b2f(u.z); v.w = b2f(u.w);
      }
      const int rs_ = r ^ (((kk >> 1) & 7) << 2);
      const int kb = kk * 4;
      Is[kb + 0][rs_] = v.x;
      Is[kb + 1][rs_] = v.y;
      Is[kb + 2][rs_] = v.z;
      Is[kb + 3][rs_] = v.w;
    }
    __syncthreads();

#pragma unroll 4
    for (int k = 0; k < 64; ++k) {
      const int X  = ((k >> 3) & 7) << 2;
      const int b1 = r0 ^ X;
      const int b2 = b1 ^ 4;
      const float4 i1 = *reinterpret_cast<const float4*>(&Is[k][b1]);
      const float4 i2 = *reinterpret_cast<const float4*>(&Is[k][b2]);
      const float4 w1 = *reinterpret_cast<const float4*>(&Ws[k][c0]);
      const float4 w2 = *reinterpret_cast<const float4*>(&Ws[k][c0 + 64]);
      const float iv[8] = {i1.x, i1.y, i1.z, i1.w, i2.x, i2.y, i2.z, i2.w};
      const float wv[8] = {w1.x, w1.y, w1.z, w1.w, w2.x, w2.y, w2.z, w2.w};
#pragma unroll
      for (int r = 0; r < 8; ++r)
#pragma unroll
        for (int c = 0; c < 8; ++c)
          acc[r][c] = fmaf(iv[r], wv[c], acc[r][c]);
    }
  }

  float bv[8];
#pragma unroll
  for (int c = 0; c < 4; ++c) { bv[c] = bias[c0 + c]; bv[c + 4] = bias[c0 + 64 + c]; }
#pragma unroll
  for (int r = 0; r < 8; ++r) {
    const int grow = row0 + r0 + r;
    if (grow < M) {
      ushort4 p1, p2;
      p1.x = (unsigned short)f2b(fmaxf(acc[r][0] + bv[0], 0.f));
      p1.y = (unsigned short)f2b(fmaxf(acc[r][1] + bv[1], 0.f));
      p1.z = (unsigned short)f2b(fmaxf(acc[r][2] + bv[2], 0.f));
      p1.w = (unsigned short)f2b(fmaxf(acc[r][3] + bv[3], 0.f));
      p2.x = (unsigned short)f2b(fmaxf(acc[r][4] + bv[4], 0.f));
      p2.y = (unsigned short)f2b(fmaxf(acc[r][5] + bv[5], 0.f));
      p2.z = (unsigned short)f2b(fmaxf(acc[r][6] + bv[6], 0.f));
      p2.w = (unsigned short)f2b(fmaxf(acc[r][7] + bv[7], 0.f));
      *reinterpret_cast<ushort4*>(&outb[(size_t)grow * 128 + c0])      = p1;
      *reinterpret_cast<ushort4*>(&outb[(size_t)grow * 128 + c0 + 64]) = p2;
    }
  }
}

// ======== segment-mean pooling (batch sorted, bf16 input) ========
__global__ __launch_bounds__(128) void k_pool(const unsigned short* __restrict__ h,
                                              const int* __restrict__ batch,
                                              float* __restrict__ sums,
                                              int* __restrict__ cnts)
{
  const int d = threadIdx.x;
  const int start = blockIdx.x * 256;
  if (start >= NN) return;
  const int end = min(start + 256, NN);
  int g = batch[start];
  float acc = 0.f;
  int cnt = 0;
  for (int i = start; i < end; ++i) {
    const int gi = batch[i];
    if (gi != g) {
      atomAddF(&sums[g * DF + d], acc);
      if (d == 0) atomicAdd(&cnts[g], cnt);
      acc = 0.f; cnt = 0; g = gi;
    }
    acc += b2f(h[(size_t)i * DF + d]);
    ++cnt;
  }
  atomAddF(&sums[g * DF + d], acc);
  if (d == 0) atomicAdd(&cnts[g], cnt);
}

// ======== head ========
__global__ __launch_bounds__(256) void k_head(const float* __restrict__ sums,
                                              const int* __restrict__ cnts,
                                              const float* __restrict__ Wfc,
                                              const float* __restrict__ bfc,
                                              float* __restrict__ out)
{
  for (int o = threadIdx.x; o < NG * NC; o += 256) {
    const int g = o / NC, c = o % NC;
    const float inv = 1.f / fmaxf((float)cnts[g], 1.f);
    float z = bfc[c];
    for (int k = 0; k < DF; ++k)
      z = fmaf(sums[g * DF + k] * inv, Wfc[k * NC + c], z);
    out[o] = 1.f / (1.f + expf(-z));
  }
}

extern "C" void kernel_launch(void* const* d_in, const int* in_sizes, int n_in,
                              void* d_out, int out_size, void* d_ws, size_t ws_size,
                              hipStream_t stream)
{
  const float* x   = (const float*)d_in[0];
  const int*   ei  = (const int*)d_in[1];
  const int* batch = (const int*)d_in[2];
  const float* W1a = (const float*)d_in[3];
  const float* b1a = (const float*)d_in[4];
  const float* W1b = (const float*)d_in[5];
  const float* b1b = (const float*)d_in[6];
  const float* W2a = (const float*)d_in[7];
  const float* b2a = (const float*)d_in[8];
  const float* W2b = (const float*)d_in[9];
  const float* b2b = (const float*)d_in[10];
  const float* Wfc = (const float*)d_in[11];
  const float* bfc = (const float*)d_in[12];
  float* out = (float*)d_out;

  const int* src = ei;           // edge_index[0]
  const int* dst = ei + NE;      // edge_index[1]

  // ws layout (bytes): xb | A | H  (bf16, 12.8MB each) | sums | cnts | deg | rs | cur | part | es
  unsigned short* xb = (unsigned short*)d_ws;
  unsigned short* A  = xb + (size_t)NN * DF;
  unsigned short* H  = A + (size_t)NN * DF;
  float* sums = (float*)(H + (size_t)NN * DF);
  int*   cnts = (int*)(sums + NG * DF);
  int*   deg  = cnts + 64;
  int*   rs   = deg + NN;
  int*   cur  = rs + (NN + 1);
  int*   part = cur + NN;
  int*   es   = part + 64;

  const int gemm_grid   = (NN + 127) / 128;        // 391
  const int gather_grid = (NN * 64 + 255) / 256;   // 12500
  const int edge_grid   = (NE + 255) / 256;        // 3125

  // ---- cast + CSR build ----
  k_cast<<<(NN * DF / 4 + 255) / 256, 256, 0, stream>>>(x, xb);
  hipMemsetAsync(deg, 0, NN * sizeof(int), stream);
  k_hist<<<edge_grid, 256, 0, stream>>>(dst, deg);
  k_scan_a<<<SCAN_NB, 1024, 0, stream>>>(deg, rs, part);
  k_scan_b<<<1, 64, 0, stream>>>(part, rs);
  k_scan_c<<<(NN + 255) / 256, 256, 0, stream>>>(rs, part, cur);
  k_fill<<<edge_grid, 256, 0, stream>>>(src, dst, cur, es);

  // ---- conv1 ----
  k_gather<<<gather_grid, 256, 0, stream>>>(xb, A, rs, es);
  k_gemm<<<gemm_grid, 256, 0, stream>>>(A, W1a, b1a, A, NN);
  k_gemm<<<gemm_grid, 256, 0, stream>>>(A, W1b, b1b, A, NN);

  // ---- conv2 ----
  k_gather<<<gather_grid, 256, 0, stream>>>(A, H, rs, es);
  k_gemm<<<gemm_grid, 256, 0, stream>>>(H, W2a, b2a, H, NN);
  k_gemm<<<gemm_grid, 256, 0, stream>>>(H, W2b, b2b, H, NN);

  // ---- pool + head ----
  hipMemsetAsync(sums, 0, (size_t)NG * DF * sizeof(float) + NG * sizeof(int), stream);
  k_pool<<<(NN + 255) / 256, 128, 0, stream>>>(H, batch, sums, cnts);
  k_head<<<1, 256, 0, stream>>>(sums, cnts, Wfc, bfc, out);
}

// Round 4
// 310.539 us; speedup vs baseline: 9.3920x; 1.3304x over previous
//
#include <hip/hip_runtime.h>

#define NN 50000
#define NE 800000
#define DF 128
#define NG 64
#define NC 10
#define SCAN_NB 49   // ceil(NN/1024)

typedef short bf16x8 __attribute__((ext_vector_type(8)));   // 8 bf16 in 4 VGPRs
typedef float f32x4  __attribute__((ext_vector_type(4)));

__device__ __forceinline__ void atomAddF(float* p, float v) {
  __hip_atomic_fetch_add(p, v, __ATOMIC_RELAXED, __HIP_MEMORY_SCOPE_AGENT);
}
__device__ __forceinline__ float b2f(unsigned short u) {
  union { unsigned int i; float f; } v; v.i = (unsigned int)u << 16; return v.f;
}
__device__ __forceinline__ unsigned int f2b(float f) {   // RNE, finite inputs
  unsigned int i = __float_as_uint(f);
  return (i + 0x7fffu + ((i >> 16) & 1u)) >> 16;
}

// ======== cast x (fp32) -> xb (bf16) ========
__global__ __launch_bounds__(256) void k_cast(const float* __restrict__ x,
                                              unsigned short* __restrict__ xb)
{
  const int i = blockIdx.x * 256 + threadIdx.x;       // 4 floats per thread
  if (i * 4 >= NN * DF) return;
  const float4 v = reinterpret_cast<const float4*>(x)[i];
  uint2 o;
  o.x = f2b(v.x) | (f2b(v.y) << 16);
  o.y = f2b(v.z) | (f2b(v.w) << 16);
  reinterpret_cast<uint2*>(xb)[i] = o;
}

// ======== transpose + cast the 4 conv weights: Wt[mat][n][k] = bf16(W[mat][k][n]) ========
__global__ __launch_bounds__(256) void k_prepw(const float* __restrict__ W0,
                                               const float* __restrict__ W1,
                                               const float* __restrict__ W2,
                                               const float* __restrict__ W3,
                                               unsigned short* __restrict__ Wt)
{
  const int o = blockIdx.x * 256 + threadIdx.x;   // 4 * 2048 threads, 8 elems each
  if (o >= 4 * 2048) return;
  const int mat = o >> 11;
  const float* W = (mat == 0) ? W0 : (mat == 1) ? W1 : (mat == 2) ? W2 : W3;
  const int rem = o & 2047;
  const int n  = rem >> 4;
  const int k0 = (rem & 15) * 8;
  unsigned int u[8];
#pragma unroll
  for (int j = 0; j < 8; ++j) u[j] = f2b(W[(size_t)(k0 + j) * DF + n]);
  uint4 p;
  p.x = u[0] | (u[1] << 16);
  p.y = u[2] | (u[3] << 16);
  p.z = u[4] | (u[5] << 16);
  p.w = u[6] | (u[7] << 16);
  *reinterpret_cast<uint4*>(Wt + (size_t)mat * DF * DF + (size_t)n * DF + k0) = p;
}

// ======== CSR build ========
__global__ __launch_bounds__(256) void k_hist(const int* __restrict__ dst,
                                              int* __restrict__ deg)
{
  int e = blockIdx.x * 256 + threadIdx.x;
  if (e < NE) atomicAdd(&deg[dst[e]], 1);
}

__global__ __launch_bounds__(1024) void k_scan_a(const int* __restrict__ deg,
                                                 int* __restrict__ rs,
                                                 int* __restrict__ part)
{
  __shared__ int sm[1024];
  const int t = threadIdx.x;
  const int i = blockIdx.x * 1024 + t;
  const int d = (i < NN) ? deg[i] : 0;
  sm[t] = d;
  __syncthreads();
  for (int off = 1; off < 1024; off <<= 1) {
    int u = (t >= off) ? sm[t - off] : 0;
    __syncthreads();
    sm[t] += u;
    __syncthreads();
  }
  if (i < NN) rs[i] = sm[t] - d;
  if (t == 1023) part[blockIdx.x] = sm[t];
}

__global__ __launch_bounds__(64) void k_scan_b(int* __restrict__ part,
                                               int* __restrict__ rs)
{
  __shared__ int sm[64];
  const int t = threadIdx.x;
  const int v = (t < SCAN_NB) ? part[t] : 0;
  sm[t] = v;
  __syncthreads();
  for (int off = 1; off < 64; off <<= 1) {
    int u = (t >= off) ? sm[t - off] : 0;
    __syncthreads();
    sm[t] += u;
    __syncthreads();
  }
  part[t] = sm[t] - v;
  if (t == 63) rs[NN] = sm[63];
}

__global__ __launch_bounds__(256) void k_scan_c(int* __restrict__ rs,
                                                const int* __restrict__ part,
                                                int* __restrict__ cur)
{
  const int i = blockIdx.x * 256 + threadIdx.x;
  if (i < NN) {
    const int v = rs[i] + part[i >> 10];
    rs[i] = v;
    cur[i] = v;
  }
}

__global__ __launch_bounds__(256) void k_fill(const int* __restrict__ src,
                                              const int* __restrict__ dst,
                                              int* __restrict__ cur,
                                              int* __restrict__ es)
{
  int e = blockIdx.x * 256 + threadIdx.x;
  if (e < NE) {
    int p = atomicAdd(&cur[dst[e]], 1);
    es[p] = src[e];
  }
}

// ======== gather-aggregate (bf16): out[i] = feat[i] + sum_j feat[es_j] ========
__global__ __launch_bounds__(256) void k_gather(const unsigned short* __restrict__ feat,
                                                unsigned short* __restrict__ outp,
                                                const int* __restrict__ rs,
                                                const int* __restrict__ es)
{
  const int wid  = (blockIdx.x * 256 + threadIdx.x) >> 6;
  const int lane = threadIdx.x & 63;
  if (wid >= NN) return;
  const int beg = rs[wid];
  const int end = rs[wid + 1];
  const int off = lane * 2;

  const unsigned int self = *reinterpret_cast<const unsigned int*>(feat + (size_t)wid * DF + off);
  float ax = b2f(self & 0xffff), ay = b2f(self >> 16);
  int j = beg;
  for (; j + 3 < end; j += 4) {
    const int s0 = es[j], s1 = es[j + 1], s2 = es[j + 2], s3 = es[j + 3];
    const unsigned int u0 = *reinterpret_cast<const unsigned int*>(feat + (size_t)s0 * DF + off);
    const unsigned int u1 = *reinterpret_cast<const unsigned int*>(feat + (size_t)s1 * DF + off);
    const unsigned int u2 = *reinterpret_cast<const unsigned int*>(feat + (size_t)s2 * DF + off);
    const unsigned int u3 = *reinterpret_cast<const unsigned int*>(feat + (size_t)s3 * DF + off);
    ax += b2f(u0 & 0xffff) + b2f(u1 & 0xffff) + b2f(u2 & 0xffff) + b2f(u3 & 0xffff);
    ay += b2f(u0 >> 16)    + b2f(u1 >> 16)    + b2f(u2 >> 16)    + b2f(u3 >> 16);
  }
  for (; j < end; ++j) {
    const unsigned int u0 = *reinterpret_cast<const unsigned int*>(feat + (size_t)es[j] * DF + off);
    ax += b2f(u0 & 0xffff);
    ay += b2f(u0 >> 16);
  }
  const unsigned int o = f2b(ax) | (f2b(ay) << 16);
  *reinterpret_cast<unsigned int*>(outp + (size_t)wid * DF + off) = o;
}

// ======== MFMA GEMM: out(bf16) = relu(A(bf16) @ W + bias) via D = Wt-frag x Arow-frag ========
// Wave-self-contained (16 rows/wave, 64 rows/block), no LDS, in-place safe.
// mfma_f32_16x16x32_bf16: A/B frag k = (lane>>4)*8 + j (contiguous 8);
// C/D: col = lane&15 (node), row = (lane>>4)*4 + reg (feature).
__global__ __launch_bounds__(256) void k_gemm(const unsigned short* __restrict__ Ab,
                                              const unsigned short* __restrict__ Wt,
                                              const float* __restrict__ bias,
                                              unsigned short* __restrict__ outb, int M)
{
  const int lane = threadIdx.x & 63;
  const int w    = threadIdx.x >> 6;
  const int m0   = blockIdx.x * 64 + w * 16;
  const int col  = lane & 15;
  const int kq   = lane >> 4;          // 0..3
  const int m    = m0 + col;
  const int mld  = (m < M) ? m : (M - 1);

  f32x4 acc[8];
#pragma unroll
  for (int nf = 0; nf < 8; ++nf) acc[nf] = (f32x4){0.f, 0.f, 0.f, 0.f};

  const unsigned short* arow = Ab + (size_t)mld * DF + kq * 8;
#pragma unroll
  for (int s = 0; s < 4; ++s) {
    const bf16x8 bfrag = *reinterpret_cast<const bf16x8*>(arow + s * 32);
#pragma unroll
    for (int nf = 0; nf < 8; ++nf) {
      const bf16x8 afrag =
          *reinterpret_cast<const bf16x8*>(Wt + (size_t)(nf * 16 + col) * DF + s * 32 + kq * 8);
      acc[nf] = __builtin_amdgcn_mfma_f32_16x16x32_bf16(afrag, bfrag, acc[nf], 0, 0, 0);
    }
  }

  if (m < M) {
#pragma unroll
    for (int nf = 0; nf < 8; ++nf) {
      const float4 bv = *reinterpret_cast<const float4*>(bias + nf * 16 + kq * 4);
      ushort4 p;
      p.x = (unsigned short)f2b(fmaxf(acc[nf][0] + bv.x, 0.f));
      p.y = (unsigned short)f2b(fmaxf(acc[nf][1] + bv.y, 0.f));
      p.z = (unsigned short)f2b(fmaxf(acc[nf][2] + bv.z, 0.f));
      p.w = (unsigned short)f2b(fmaxf(acc[nf][3] + bv.w, 0.f));
      *reinterpret_cast<ushort4*>(outb + (size_t)m * DF + nf * 16 + kq * 4) = p;
    }
  }
}

// ======== segment-mean pooling: one wave per 32 contiguous nodes ========
__global__ __launch_bounds__(256) void k_pool(const unsigned short* __restrict__ h,
                                              const int* __restrict__ batch,
                                              float* __restrict__ sums,
                                              int* __restrict__ cnts)
{
  const int wv   = (blockIdx.x * 256 + threadIdx.x) >> 6;
  const int lane = threadIdx.x & 63;
  const int n0 = wv * 32;
  if (n0 >= NN) return;
  const int n1 = min(n0 + 32, NN);
  const int off = lane * 2;

  const int gfirst = batch[n0];
  const int glast  = batch[n1 - 1];
  float ax = 0.f, ay = 0.f;

  if (gfirst == glast) {          // fast path: whole chunk in one graph
#pragma unroll 4
    for (int i = n0; i < n1; ++i) {
      const unsigned int u = *reinterpret_cast<const unsigned int*>(h + (size_t)i * DF + off);
      ax += b2f(u & 0xffff);
      ay += b2f(u >> 16);
    }
    atomAddF(&sums[gfirst * DF + off],     ax);
    atomAddF(&sums[gfirst * DF + off + 1], ay);
    if (lane == 0) atomicAdd(&cnts[gfirst], n1 - n0);
  } else {
    int g = gfirst, cnt = 0;
    for (int i = n0; i < n1; ++i) {
      const int gi = batch[i];
      if (gi != g) {
        atomAddF(&sums[g * DF + off],     ax);
        atomAddF(&sums[g * DF + off + 1], ay);
        if (lane == 0) atomicAdd(&cnts[g], cnt);
        ax = 0.f; ay = 0.f; cnt = 0; g = gi;
      }
      const unsigned int u = *reinterpret_cast<const unsigned int*>(h + (size_t)i * DF + off);
      ax += b2f(u & 0xffff);
      ay += b2f(u >> 16);
      ++cnt;
    }
    atomAddF(&sums[g * DF + off],     ax);
    atomAddF(&sums[g * DF + off + 1], ay);
    if (lane == 0) atomicAdd(&cnts[g], cnt);
  }
}

// ======== head ========
__global__ __launch_bounds__(256) void k_head(const float* __restrict__ sums,
                                              const int* __restrict__ cnts,
                                              const float* __restrict__ Wfc,
                                              const float* __restrict__ bfc,
                                              float* __restrict__ out)
{
  for (int o = threadIdx.x; o < NG * NC; o += 256) {
    const int g = o / NC, c = o % NC;
    const float inv = 1.f / fmaxf((float)cnts[g], 1.f);
    float z = bfc[c];
    for (int k = 0; k < DF; ++k)
      z = fmaf(sums[g * DF + k] * inv, Wfc[k * NC + c], z);
    out[o] = 1.f / (1.f + expf(-z));
  }
}

extern "C" void kernel_launch(void* const* d_in, const int* in_sizes, int n_in,
                              void* d_out, int out_size, void* d_ws, size_t ws_size,
                              hipStream_t stream)
{
  const float* x   = (const float*)d_in[0];
  const int*   ei  = (const int*)d_in[1];
  const int* batch = (const int*)d_in[2];
  const float* W1a = (const float*)d_in[3];
  const float* b1a = (const float*)d_in[4];
  const float* W1b = (const float*)d_in[5];
  const float* b1b = (const float*)d_in[6];
  const float* W2a = (const float*)d_in[7];
  const float* b2a = (const float*)d_in[8];
  const float* W2b = (const float*)d_in[9];
  const float* b2b = (const float*)d_in[10];
  const float* Wfc = (const float*)d_in[11];
  const float* bfc = (const float*)d_in[12];
  float* out = (float*)d_out;

  const int* src = ei;           // edge_index[0]
  const int* dst = ei + NE;      // edge_index[1]

  // ws: xb | A | H (bf16) | Wt x4 (bf16) | sums | cnts | deg | rs | cur | part | es
  unsigned short* xb = (unsigned short*)d_ws;
  unsigned short* A  = xb + (size_t)NN * DF;
  unsigned short* H  = A + (size_t)NN * DF;
  unsigned short* Wt = H + (size_t)NN * DF;
  float* sums = (float*)(Wt + (size_t)4 * DF * DF);
  int*   cnts = (int*)(sums + NG * DF);
  int*   deg  = cnts + 64;
  int*   rs   = deg + NN;
  int*   cur  = rs + (NN + 1);
  int*   part = cur + NN;
  int*   es   = part + 64;

  unsigned short* Wt1a = Wt;
  unsigned short* Wt1b = Wt + DF * DF;
  unsigned short* Wt2a = Wt + 2 * DF * DF;
  unsigned short* Wt2b = Wt + 3 * DF * DF;

  const int gemm_grid   = (NN + 63) / 64;          // 782
  const int gather_grid = (NN * 64 + 255) / 256;   // 12500
  const int edge_grid   = (NE + 255) / 256;        // 3125
  const int pool_grid   = ((NN + 31) / 32 + 3) / 4;  // 391

  // ---- prep: cast x, transpose weights, CSR build ----
  k_cast<<<(NN * DF / 4 + 255) / 256, 256, 0, stream>>>(x, xb);
  k_prepw<<<32, 256, 0, stream>>>(W1a, W1b, W2a, W2b, Wt);
  hipMemsetAsync(deg, 0, NN * sizeof(int), stream);
  k_hist<<<edge_grid, 256, 0, stream>>>(dst, deg);
  k_scan_a<<<SCAN_NB, 1024, 0, stream>>>(deg, rs, part);
  k_scan_b<<<1, 64, 0, stream>>>(part, rs);
  k_scan_c<<<(NN + 255) / 256, 256, 0, stream>>>(rs, part, cur);
  k_fill<<<edge_grid, 256, 0, stream>>>(src, dst, cur, es);

  // ---- conv1 ----
  k_gather<<<gather_grid, 256, 0, stream>>>(xb, A, rs, es);
  k_gemm<<<gemm_grid, 256, 0, stream>>>(A, Wt1a, b1a, A, NN);
  k_gemm<<<gemm_grid, 256, 0, stream>>>(A, Wt1b, b1b, A, NN);

  // ---- conv2 ----
  k_gather<<<gather_grid, 256, 0, stream>>>(A, H, rs, es);
  k_gemm<<<gemm_grid, 256, 0, stream>>>(H, Wt2a, b2a, H, NN);
  k_gemm<<<gemm_grid, 256, 0, stream>>>(H, Wt2b, b2b, H, NN);

  // ---- pool + head ----
  hipMemsetAsync(sums, 0, (size_t)NG * DF * sizeof(float) + NG * sizeof(int), stream);
  k_pool<<<pool_grid, 256, 0, stream>>>(H, batch, sums, cnts);
  k_head<<<1, 256, 0, stream>>>(sums, cnts, Wfc, bfc, out);
}

// Round 5
// 242.481 us; speedup vs baseline: 12.0281x; 1.2807x over previous
//
#include <hip/hip_runtime.h>

#define NN 50000
#define NE 800000
#define DF 128
#define NG 64
#define NC 10
#define SCAN_NB 49        // ceil(NN/1024)
#define NBK 98            // ceil(NN/512) coarse buckets (dst>>9)
#define PART_CHUNK 4096
#define PART_GRID 196     // 196*4096 >= 800000
#define FINE_CAP 12288    // LDS u16 slots per bucket (avg 8163, max ~8600)

typedef short bf16x8 __attribute__((ext_vector_type(8)));
typedef float f32x4  __attribute__((ext_vector_type(4)));

__device__ __forceinline__ void atomAddF(float* p, float v) {
  __hip_atomic_fetch_add(p, v, __ATOMIC_RELAXED, __HIP_MEMORY_SCOPE_AGENT);
}
__device__ __forceinline__ float b2f(unsigned short u) {
  union { unsigned int i; float f; } v; v.i = (unsigned int)u << 16; return v.f;
}
__device__ __forceinline__ unsigned int f2b(float f) {
  unsigned int i = __float_as_uint(f);
  return (i + 0x7fffu + ((i >> 16) & 1u)) >> 16;
}

// ======== cast x (fp32) -> xb (bf16) ========
__global__ __launch_bounds__(256) void k_cast(const float* __restrict__ x,
                                              unsigned short* __restrict__ xb)
{
  const int i = blockIdx.x * 256 + threadIdx.x;
  if (i * 4 >= NN * DF) return;
  const float4 v = reinterpret_cast<const float4*>(x)[i];
  uint2 o;
  o.x = f2b(v.x) | (f2b(v.y) << 16);
  o.y = f2b(v.z) | (f2b(v.w) << 16);
  reinterpret_cast<uint2*>(xb)[i] = o;
}

// ======== transpose + cast weights: Wt[mat][n][k] = bf16(W[mat][k][n]) ========
__global__ __launch_bounds__(256) void k_prepw(const float* __restrict__ W0,
                                               const float* __restrict__ W1,
                                               const float* __restrict__ W2,
                                               const float* __restrict__ W3,
                                               unsigned short* __restrict__ Wt)
{
  const int o = blockIdx.x * 256 + threadIdx.x;
  if (o >= 4 * 2048) return;
  const int mat = o >> 11;
  const float* W = (mat == 0) ? W0 : (mat == 1) ? W1 : (mat == 2) ? W2 : W3;
  const int rem = o & 2047;
  const int n  = rem >> 4;
  const int k0 = (rem & 15) * 8;
  unsigned int u[8];
#pragma unroll
  for (int j = 0; j < 8; ++j) u[j] = f2b(W[(size_t)(k0 + j) * DF + n]);
  uint4 p;
  p.x = u[0] | (u[1] << 16);
  p.y = u[2] | (u[3] << 16);
  p.z = u[4] | (u[5] << 16);
  p.w = u[6] | (u[7] << 16);
  *reinterpret_cast<uint4*>(Wt + (size_t)mat * DF * DF + (size_t)n * DF + k0) = p;
}

// ======== CSR build ========
__global__ __launch_bounds__(256) void k_hist(const int* __restrict__ dst,
                                              int* __restrict__ deg)
{
  int e = blockIdx.x * 256 + threadIdx.x;
  if (e < NE) atomicAdd(&deg[dst[e]], 1);
}

__global__ __launch_bounds__(1024) void k_scan_a(const int* __restrict__ deg,
                                                 int* __restrict__ rs,
                                                 int* __restrict__ part)
{
  __shared__ int sm[1024];
  const int t = threadIdx.x;
  const int i = blockIdx.x * 1024 + t;
  const int d = (i < NN) ? deg[i] : 0;
  sm[t] = d;
  __syncthreads();
  for (int off = 1; off < 1024; off <<= 1) {
    int u = (t >= off) ? sm[t - off] : 0;
    __syncthreads();
    sm[t] += u;
    __syncthreads();
  }
  if (i < NN) rs[i] = sm[t] - d;
  if (t == 1023) part[blockIdx.x] = sm[t];
}

__global__ __launch_bounds__(64) void k_scan_b(int* __restrict__ part,
                                               int* __restrict__ rs)
{
  __shared__ int sm[64];
  const int t = threadIdx.x;
  const int v = (t < SCAN_NB) ? part[t] : 0;
  sm[t] = v;
  __syncthreads();
  for (int off = 1; off < 64; off <<= 1) {
    int u = (t >= off) ? sm[t - off] : 0;
    __syncthreads();
    sm[t] += u;
    __syncthreads();
  }
  part[t] = sm[t] - v;
  if (t == 63) rs[NN] = sm[63];
}

__global__ __launch_bounds__(256) void k_scan_c(int* __restrict__ rs,
                                                const int* __restrict__ part,
                                                int* __restrict__ cur)
{
  const int i = blockIdx.x * 256 + threadIdx.x;
  if (i < NN) {
    const int v = rs[i] + part[i >> 10];
    rs[i] = v;
    cur[i] = v;
  }
}

// per-bucket cursors for the partition pass: cur_b[b] = rs[b*512]
__global__ __launch_bounds__(128) void k_curb(const int* __restrict__ rs,
                                              int* __restrict__ cur_b)
{
  const int b = threadIdx.x;
  if (b < NBK) cur_b[b] = rs[min(b << 9, NN)];
}

// ---- phase B: partition edges into NBK coarse buckets, LDS counting sort ----
// pack = (bucket<<25) | (dstlocal<<16) | src   (7+9+16 bits)
__global__ __launch_bounds__(256) void k_part(const int* __restrict__ src,
                                              const int* __restrict__ dst,
                                              int* __restrict__ cur_b,
                                              unsigned int* __restrict__ ePack)
{
  __shared__ unsigned int stage[PART_CHUNK];
  __shared__ int lhist[128], lcnt[128], lcur[128], gbase[128];
  const int tid = threadIdx.x;
  const int e0  = blockIdx.x * PART_CHUNK;
  const int nE  = min(PART_CHUNK, NE - e0);

  for (int i = tid; i < 128; i += 256) lhist[i] = 0;
  __syncthreads();

  unsigned int pk[16];
  int bk[16];
#pragma unroll
  for (int i = 0; i < 16; ++i) {
    const int e = e0 + i * 256 + tid;
    if (e < NE) {
      const int d = dst[e];
      const int s = src[e];
      const int b = d >> 9;
      bk[i] = b;
      pk[i] = ((unsigned int)b << 25) | ((unsigned int)(d & 511) << 16) | (unsigned int)s;
      atomicAdd(&lhist[b], 1);
    } else {
      bk[i] = -1;
    }
  }
  __syncthreads();
  for (int i = tid; i < 128; i += 256) lcnt[i] = lhist[i];
  __syncthreads();
  // inclusive scan over 128 entries
  for (int off = 1; off < 128; off <<= 1) {
    int v = 0;
    if (tid < 128 && tid >= off) v = lhist[tid - off];
    __syncthreads();
    if (tid < 128) lhist[tid] += v;
    __syncthreads();
  }
  if (tid < 128) lcur[tid] = lhist[tid] - lcnt[tid];   // local exclusive offset
  __syncthreads();
#pragma unroll
  for (int i = 0; i < 16; ++i) {
    if (bk[i] >= 0) {
      const int pos = atomicAdd(&lcur[bk[i]], 1);
      stage[pos] = pk[i];
    }
  }
  __syncthreads();
  if (tid < NBK) {
    const int c = lcnt[tid];
    if (c > 0) gbase[tid] = atomicAdd(&cur_b[tid], c);
  }
  __syncthreads();
  for (int idx = tid; idx < nE; idx += 256) {
    const unsigned int p = stage[idx];
    const int b = (int)(p >> 25);
    const int loff = lhist[b] - lcnt[b];
    ePack[gbase[b] + (idx - loff)] = p;
  }
}

// ---- phase C: one block per bucket; LDS scatter then coalesced write ----
__global__ __launch_bounds__(256) void k_fine(const unsigned int* __restrict__ ePack,
                                              const int* __restrict__ rs,
                                              int* __restrict__ cur,
                                              int* __restrict__ es)
{
  __shared__ unsigned short les[FINE_CAP];
  __shared__ int lcur[512];
  const int tid   = threadIdx.x;
  const int b     = blockIdx.x;
  const int nbase = b << 9;
  const int nend  = min(nbase + 512, NN);
  const int nwin  = nend - nbase;
  const int wbase = rs[nbase];
  const int wend  = rs[nend];
  const int wlen  = wend - wbase;

  if (wlen <= FINE_CAP) {
    for (int i = tid; i < nwin; i += 256) lcur[i] = rs[nbase + i] - wbase;
    __syncthreads();
    for (int idx = wbase + tid; idx < wend; idx += 256) {
      const unsigned int p = ePack[idx];
      const int dl = (int)((p >> 16) & 511);
      const int pos = atomicAdd(&lcur[dl], 1);
      les[pos] = (unsigned short)(p & 0xffffu);
    }
    __syncthreads();
    for (int i = tid; i < wlen; i += 256) es[wbase + i] = (int)les[i];
  } else {
    // fallback (statistically unreachable): global scatter
    for (int idx = wbase + tid; idx < wend; idx += 256) {
      const unsigned int p = ePack[idx];
      const int d = nbase + (int)((p >> 16) & 511);
      const int pos = atomicAdd(&cur[d], 1);
      es[pos] = (int)(p & 0xffffu);
    }
  }
}

// ======== gather-aggregate (bf16): out[i] = feat[i] + sum_j feat[es_j] ========
__global__ __launch_bounds__(256) void k_gather(const unsigned short* __restrict__ feat,
                                                unsigned short* __restrict__ outp,
                                                const int* __restrict__ rs,
                                                const int* __restrict__ es)
{
  const int wid  = (blockIdx.x * 256 + threadIdx.x) >> 6;
  const int lane = threadIdx.x & 63;
  if (wid >= NN) return;
  const int beg = rs[wid];
  const int end = rs[wid + 1];
  const int off = lane * 2;

  const unsigned int self = *reinterpret_cast<const unsigned int*>(feat + (size_t)wid * DF + off);
  float ax = b2f(self & 0xffff), ay = b2f(self >> 16);
  int j = beg;
  for (; j + 3 < end; j += 4) {
    const int s0 = es[j], s1 = es[j + 1], s2 = es[j + 2], s3 = es[j + 3];
    const unsigned int u0 = *reinterpret_cast<const unsigned int*>(feat + (size_t)s0 * DF + off);
    const unsigned int u1 = *reinterpret_cast<const unsigned int*>(feat + (size_t)s1 * DF + off);
    const unsigned int u2 = *reinterpret_cast<const unsigned int*>(feat + (size_t)s2 * DF + off);
    const unsigned int u3 = *reinterpret_cast<const unsigned int*>(feat + (size_t)s3 * DF + off);
    ax += b2f(u0 & 0xffff) + b2f(u1 & 0xffff) + b2f(u2 & 0xffff) + b2f(u3 & 0xffff);
    ay += b2f(u0 >> 16)    + b2f(u1 >> 16)    + b2f(u2 >> 16)    + b2f(u3 >> 16);
  }
  for (; j < end; ++j) {
    const unsigned int u0 = *reinterpret_cast<const unsigned int*>(feat + (size_t)es[j] * DF + off);
    ax += b2f(u0 & 0xffff);
    ay += b2f(u0 >> 16);
  }
  const unsigned int o = f2b(ax) | (f2b(ay) << 16);
  *reinterpret_cast<unsigned int*>(outp + (size_t)wid * DF + off) = o;
}

// ======== MFMA GEMM, W resident in registers; 4 tiles of 16 rows per wave ========
__global__ __launch_bounds__(256) void k_gemm(const unsigned short* __restrict__ Ab,
                                              const unsigned short* __restrict__ Wt,
                                              const float* __restrict__ bias,
                                              unsigned short* __restrict__ outb, int M)
{
  const int lane = threadIdx.x & 63;
  const int w    = threadIdx.x >> 6;
  const int col  = lane & 15;
  const int kq   = lane >> 4;

  bf16x8 wf[8][4];
#pragma unroll
  for (int nf = 0; nf < 8; ++nf)
#pragma unroll
    for (int s = 0; s < 4; ++s)
      wf[nf][s] = *reinterpret_cast<const bf16x8*>(
          Wt + (size_t)(nf * 16 + col) * DF + s * 32 + kq * 8);

  float4 bv[8];
#pragma unroll
  for (int nf = 0; nf < 8; ++nf)
    bv[nf] = *reinterpret_cast<const float4*>(bias + nf * 16 + kq * 4);

  const int rbase = blockIdx.x * 256;

  // software pipeline: preload tile 0
  int m = rbase + w * 16 + col;
  int mld = (m < M) ? m : (M - 1);
  bf16x8 bf_cur[4];
#pragma unroll
  for (int s = 0; s < 4; ++s)
    bf_cur[s] = *reinterpret_cast<const bf16x8*>(Ab + (size_t)mld * DF + s * 32 + kq * 8);

#pragma unroll
  for (int t = 0; t < 4; ++t) {
    bf16x8 bf_nxt[4];
    if (t < 3) {
      const int m2 = rbase + (t + 1) * 64 + w * 16 + col;
      const int mld2 = (m2 < M) ? m2 : (M - 1);
#pragma unroll
      for (int s = 0; s < 4; ++s)
        bf_nxt[s] = *reinterpret_cast<const bf16x8*>(Ab + (size_t)mld2 * DF + s * 32 + kq * 8);
    }
    f32x4 acc[8];
#pragma unroll
    for (int nf = 0; nf < 8; ++nf) acc[nf] = (f32x4){0.f, 0.f, 0.f, 0.f};
#pragma unroll
    for (int s = 0; s < 4; ++s)
#pragma unroll
      for (int nf = 0; nf < 8; ++nf)
        acc[nf] = __builtin_amdgcn_mfma_f32_16x16x32_bf16(wf[nf][s], bf_cur[s], acc[nf], 0, 0, 0);
    if (m < M) {
#pragma unroll
      for (int nf = 0; nf < 8; ++nf) {
        ushort4 p;
        p.x = (unsigned short)f2b(fmaxf(acc[nf][0] + bv[nf].x, 0.f));
        p.y = (unsigned short)f2b(fmaxf(acc[nf][1] + bv[nf].y, 0.f));
        p.z = (unsigned short)f2b(fmaxf(acc[nf][2] + bv[nf].z, 0.f));
        p.w = (unsigned short)f2b(fmaxf(acc[nf][3] + bv[nf].w, 0.f));
        *reinterpret_cast<ushort4*>(outb + (size_t)m * DF + nf * 16 + kq * 4) = p;
      }
    }
#pragma unroll
    for (int s = 0; s < 4; ++s) bf_cur[s] = bf_nxt[s];
    m = rbase + (t + 1) * 64 + w * 16 + col;
    mld = (m < M) ? m : (M - 1);
  }
}

// ======== segment-mean pooling: one wave per 32 contiguous nodes ========
__global__ __launch_bounds__(256) void k_pool(const unsigned short* __restrict__ h,
                                              const int* __restrict__ batch,
                                              float* __restrict__ sums,
                                              int* __restrict__ cnts)
{
  const int wv   = (blockIdx.x * 256 + threadIdx.x) >> 6;
  const int lane = threadIdx.x & 63;
  const int n0 = wv * 32;
  if (n0 >= NN) return;
  const int n1 = min(n0 + 32, NN);
  const int off = lane * 2;

  const int gfirst = batch[n0];
  const int glast  = batch[n1 - 1];
  float ax = 0.f, ay = 0.f;

  if (gfirst == glast) {
#pragma unroll 4
    for (int i = n0; i < n1; ++i) {
      const unsigned int u = *reinterpret_cast<const unsigned int*>(h + (size_t)i * DF + off);
      ax += b2f(u & 0xffff);
      ay += b2f(u >> 16);
    }
    atomAddF(&sums[gfirst * DF + off],     ax);
    atomAddF(&sums[gfirst * DF + off + 1], ay);
    if (lane == 0) atomicAdd(&cnts[gfirst], n1 - n0);
  } else {
    int g = gfirst, cnt = 0;
    for (int i = n0; i < n1; ++i) {
      const int gi = batch[i];
      if (gi != g) {
        atomAddF(&sums[g * DF + off],     ax);
        atomAddF(&sums[g * DF + off + 1], ay);
        if (lane == 0) atomicAdd(&cnts[g], cnt);
        ax = 0.f; ay = 0.f; cnt = 0; g = gi;
      }
      const unsigned int u = *reinterpret_cast<const unsigned int*>(h + (size_t)i * DF + off);
      ax += b2f(u & 0xffff);
      ay += b2f(u >> 16);
      ++cnt;
    }
    atomAddF(&sums[g * DF + off],     ax);
    atomAddF(&sums[g * DF + off + 1], ay);
    if (lane == 0) atomicAdd(&cnts[g], cnt);
  }
}

// ======== head ========
__global__ __launch_bounds__(256) void k_head(const float* __restrict__ sums,
                                              const int* __restrict__ cnts,
                                              const float* __restrict__ Wfc,
                                              const float* __restrict__ bfc,
                                              float* __restrict__ out)
{
  for (int o = threadIdx.x; o < NG * NC; o += 256) {
    const int g = o / NC, c = o % NC;
    const float inv = 1.f / fmaxf((float)cnts[g], 1.f);
    float z = bfc[c];
    for (int k = 0; k < DF; ++k)
      z = fmaf(sums[g * DF + k] * inv, Wfc[k * NC + c], z);
    out[o] = 1.f / (1.f + expf(-z));
  }
}

extern "C" void kernel_launch(void* const* d_in, const int* in_sizes, int n_in,
                              void* d_out, int out_size, void* d_ws, size_t ws_size,
                              hipStream_t stream)
{
  const float* x   = (const float*)d_in[0];
  const int*   ei  = (const int*)d_in[1];
  const int* batch = (const int*)d_in[2];
  const float* W1a = (const float*)d_in[3];
  const float* b1a = (const float*)d_in[4];
  const float* W1b = (const float*)d_in[5];
  const float* b1b = (const float*)d_in[6];
  const float* W2a = (const float*)d_in[7];
  const float* b2a = (const float*)d_in[8];
  const float* W2b = (const float*)d_in[9];
  const float* b2b = (const float*)d_in[10];
  const float* Wfc = (const float*)d_in[11];
  const float* bfc = (const float*)d_in[12];
  float* out = (float*)d_out;

  const int* src = ei;           // edge_index[0]
  const int* dst = ei + NE;      // edge_index[1]

  // ws: xb | A | H (bf16) | Wt x4 | sums | cnts | deg | rs | cur | part | cur_b | es | ePack
  unsigned short* xb = (unsigned short*)d_ws;
  unsigned short* A  = xb + (size_t)NN * DF;
  unsigned short* H  = A + (size_t)NN * DF;
  unsigned short* Wt = H + (size_t)NN * DF;
  float* sums = (float*)(Wt + (size_t)4 * DF * DF);
  int*   cnts = (int*)(sums + NG * DF);
  int*   deg   = cnts + 64;
  int*   rs    = deg + NN;
  int*   cur   = rs + (NN + 1);
  int*   part  = cur + NN;
  int*   cur_b = part + 64;
  int*   es    = cur_b + 128;
  unsigned int* ePack = (unsigned int*)(es + NE);

  unsigned short* Wt1a = Wt;
  unsigned short* Wt1b = Wt + DF * DF;
  unsigned short* Wt2a = Wt + 2 * DF * DF;
  unsigned short* Wt2b = Wt + 3 * DF * DF;

  const int gemm_grid   = (NN + 255) / 256;        // 196
  const int gather_grid = (NN * 64 + 255) / 256;   // 12500
  const int edge_grid   = (NE + 255) / 256;        // 3125
  const int pool_grid   = ((NN + 31) / 32 + 3) / 4;  // 391

  // ---- prep: cast x, transpose weights, CSR build ----
  k_cast<<<(NN * DF / 4 + 255) / 256, 256, 0, stream>>>(x, xb);
  k_prepw<<<32, 256, 0, stream>>>(W1a, W1b, W2a, W2b, Wt);
  hipMemsetAsync(deg, 0, NN * sizeof(int), stream);
  k_hist<<<edge_grid, 256, 0, stream>>>(dst, deg);
  k_scan_a<<<SCAN_NB, 1024, 0, stream>>>(deg, rs, part);
  k_scan_b<<<1, 64, 0, stream>>>(part, rs);
  k_scan_c<<<(NN + 255) / 256, 256, 0, stream>>>(rs, part, cur);
  k_curb<<<1, 128, 0, stream>>>(rs, cur_b);
  k_part<<<PART_GRID, 256, 0, stream>>>(src, dst, cur_b, ePack);
  k_fine<<<NBK, 256, 0, stream>>>(ePack, rs, cur, es);

  // ---- conv1 ----
  k_gather<<<gather_grid, 256, 0, stream>>>(xb, A, rs, es);
  k_gemm<<<gemm_grid, 256, 0, stream>>>(A, Wt1a, b1a, A, NN);
  k_gemm<<<gemm_grid, 256, 0, stream>>>(A, Wt1b, b1b, A, NN);

  // ---- conv2 ----
  k_gather<<<gather_grid, 256, 0, stream>>>(A, H, rs, es);
  k_gemm<<<gemm_grid, 256, 0, stream>>>(H, Wt2a, b2a, H, NN);
  k_gemm<<<gemm_grid, 256, 0, stream>>>(H, Wt2b, b2b, H, NN);

  // ---- pool + head ----
  hipMemsetAsync(sums, 0, (size_t)NG * DF * sizeof(float) + NG * sizeof(int), stream);
  k_pool<<<pool_grid, 256, 0, stream>>>(H, batch, sums, cnts);
  k_head<<<1, 256, 0, stream>>>(sums, cnts, Wfc, bfc, out);
}

// Round 6
// 203.487 us; speedup vs baseline: 14.3330x; 1.1916x over previous
//
#include <hip/hip_runtime.h>

#define NN 50000
#define NE 800000
#define DF 128
#define NG 64
#define NC 10
#define NBK 98            // ceil(NN/512) coarse buckets (dst>>9)
#define PART_CHUNK 4096
#define PART_GRID 196     // 196*4096 >= 800000
#define ACAP 12288        // arena capacity per bucket (avg 8163, max ~8600)
#define FINE_CAP 12288
#define RT 136            // h staging row stride (ushorts)

typedef short bf16x8 __attribute__((ext_vector_type(8)));
typedef float f32x4  __attribute__((ext_vector_type(4)));

__device__ __forceinline__ void atomAddF(float* p, float v) {
  __hip_atomic_fetch_add(p, v, __ATOMIC_RELAXED, __HIP_MEMORY_SCOPE_AGENT);
}
__device__ __forceinline__ float b2f(unsigned short u) {
  union { unsigned int i; float f; } v; v.i = (unsigned int)u << 16; return v.f;
}
__device__ __forceinline__ unsigned int f2b(float f) {
  unsigned int i = __float_as_uint(f);
  return (i + 0x7fffu + ((i >> 16) & 1u)) >> 16;
}

// ======== cast x (fp32) -> xb (bf16) ========
__global__ __launch_bounds__(256) void k_cast(const float* __restrict__ x,
                                              unsigned short* __restrict__ xb)
{
  const int i = blockIdx.x * 256 + threadIdx.x;
  if (i * 4 >= NN * DF) return;
  const float4 v = reinterpret_cast<const float4*>(x)[i];
  uint2 o;
  o.x = f2b(v.x) | (f2b(v.y) << 16);
  o.y = f2b(v.z) | (f2b(v.w) << 16);
  reinterpret_cast<uint2*>(xb)[i] = o;
}

// ======== transpose + cast weights: Wt[mat][n][k] = bf16(W[mat][k][n]) ========
__global__ __launch_bounds__(256) void k_prepw(const float* __restrict__ W0,
                                               const float* __restrict__ W1,
                                               const float* __restrict__ W2,
                                               const float* __restrict__ W3,
                                               unsigned short* __restrict__ Wt)
{
  const int o = blockIdx.x * 256 + threadIdx.x;
  if (o >= 4 * 2048) return;
  const int mat = o >> 11;
  const float* W = (mat == 0) ? W0 : (mat == 1) ? W1 : (mat == 2) ? W2 : W3;
  const int rem = o & 2047;
  const int n  = rem >> 4;
  const int k0 = (rem & 15) * 8;
  unsigned int u[8];
#pragma unroll
  for (int j = 0; j < 8; ++j) u[j] = f2b(W[(size_t)(k0 + j) * DF + n]);
  uint4 p;
  p.x = u[0] | (u[1] << 16);
  p.y = u[2] | (u[3] << 16);
  p.z = u[4] | (u[5] << 16);
  p.w = u[6] | (u[7] << 16);
  *reinterpret_cast<uint4*>(Wt + (size_t)mat * DF * DF + (size_t)n * DF + k0) = p;
}

// ---- partition edges into NBK bucket arenas (self-allocating, no pre-scan) ----
// pack = (bucket<<25) | (dstlocal<<16) | src
__global__ __launch_bounds__(256) void k_part(const int* __restrict__ src,
                                              const int* __restrict__ dst,
                                              int* __restrict__ cnt_b,
                                              unsigned int* __restrict__ arena)
{
  __shared__ unsigned int stage[PART_CHUNK];
  __shared__ int lhist[128], lcnt[128], lcur[128], gbase[128];
  const int tid = threadIdx.x;
  const int e0  = blockIdx.x * PART_CHUNK;
  const int nE  = min(PART_CHUNK, NE - e0);

  for (int i = tid; i < 128; i += 256) lhist[i] = 0;
  __syncthreads();

  unsigned int pk[16];
  int bk[16];
#pragma unroll
  for (int i = 0; i < 16; ++i) {
    const int e = e0 + i * 256 + tid;
    if (e < NE) {
      const int d = dst[e];
      const int s = src[e];
      const int b = d >> 9;
      bk[i] = b;
      pk[i] = ((unsigned int)b << 25) | ((unsigned int)(d & 511) << 16) | (unsigned int)s;
      atomicAdd(&lhist[b], 1);
    } else {
      bk[i] = -1;
    }
  }
  __syncthreads();
  for (int i = tid; i < 128; i += 256) lcnt[i] = lhist[i];
  __syncthreads();
  for (int off = 1; off < 128; off <<= 1) {
    int v = 0;
    if (tid < 128 && tid >= off) v = lhist[tid - off];
    __syncthreads();
    if (tid < 128) lhist[tid] += v;
    __syncthreads();
  }
  if (tid < 128) lcur[tid] = lhist[tid] - lcnt[tid];
  __syncthreads();
#pragma unroll
  for (int i = 0; i < 16; ++i) {
    if (bk[i] >= 0) {
      const int pos = atomicAdd(&lcur[bk[i]], 1);
      stage[pos] = pk[i];
    }
  }
  __syncthreads();
  if (tid < NBK) {
    const int c = lcnt[tid];
    if (c > 0) gbase[tid] = atomicAdd(&cnt_b[tid], c);
  }
  __syncthreads();
  for (int idx = tid; idx < nE; idx += 256) {
    const unsigned int p = stage[idx];
    const int b = (int)(p >> 25);
    const int loff = lhist[b] - lcnt[b];
    arena[(size_t)b * ACAP + gbase[b] + (idx - loff)] = p;
  }
}

// ---- scan the 98 bucket counts -> bucket bases; rs[NN] ----
__global__ __launch_bounds__(128) void k_bscan(const int* __restrict__ cnt_b,
                                               int* __restrict__ base_b,
                                               int* __restrict__ rs)
{
  __shared__ int sm[128];
  const int t = threadIdx.x;
  const int v = (t < NBK) ? cnt_b[t] : 0;
  sm[t] = v;
  __syncthreads();
  for (int off = 1; off < 128; off <<= 1) {
    int u = (t >= off) ? sm[t - off] : 0;
    __syncthreads();
    sm[t] += u;
    __syncthreads();
  }
  base_b[t] = sm[t] - v;
  if (t == NBK - 1) rs[NN] = sm[t];   // = NE
}

// ---- per bucket: local hist+scan of 512 nodes -> rs, sorted es ----
__global__ __launch_bounds__(256) void k_fine(const unsigned int* __restrict__ arena,
                                              const int* __restrict__ cnt_b,
                                              const int* __restrict__ base_b,
                                              int* __restrict__ rs,
                                              int* __restrict__ es)
{
  __shared__ int hist[512], offs[512], pairs[256];
  __shared__ unsigned short les[FINE_CAP];
  const int tid   = threadIdx.x;
  const int b     = blockIdx.x;
  const int cnt   = cnt_b[b];
  const int wbase = base_b[b];
  const int nbase = b << 9;
  const int nwin  = min(512, NN - nbase);
  const unsigned int* ap = arena + (size_t)b * ACAP;

  for (int i = tid; i < 512; i += 256) hist[i] = 0;
  __syncthreads();
  for (int idx = tid; idx < cnt; idx += 256)
    atomicAdd(&hist[(ap[idx] >> 16) & 511], 1);
  __syncthreads();
  const int s0 = hist[2 * tid];
  const int s1 = hist[2 * tid + 1];
  pairs[tid] = s0 + s1;
  __syncthreads();
  for (int off = 1; off < 256; off <<= 1) {
    int u = (tid >= off) ? pairs[tid - off] : 0;
    __syncthreads();
    pairs[tid] += u;
    __syncthreads();
  }
  const int ep = pairs[tid] - s0 - s1;
  offs[2 * tid]     = ep;
  offs[2 * tid + 1] = ep + s0;
  __syncthreads();
  for (int i = tid; i < nwin; i += 256) rs[nbase + i] = wbase + offs[i];
  __syncthreads();
  if (cnt <= FINE_CAP) {
    for (int idx = tid; idx < cnt; idx += 256) {
      const unsigned int p = ap[idx];
      const int pos = atomicAdd(&offs[(p >> 16) & 511], 1);
      les[pos] = (unsigned short)(p & 0xffffu);
    }
    __syncthreads();
    for (int i = tid; i < cnt; i += 256) es[wbase + i] = (int)les[i];
  } else {
    for (int idx = tid; idx < cnt; idx += 256) {
      const unsigned int p = ap[idx];
      const int pos = atomicAdd(&offs[(p >> 16) & 511], 1);
      es[wbase + pos] = (int)(p & 0xffffu);
    }
  }
}

// ======== gather-aggregate (bf16): out[i] = feat[i] + sum_j feat[es_j] ========
__global__ __launch_bounds__(256) void k_gather(const unsigned short* __restrict__ feat,
                                                unsigned short* __restrict__ outp,
                                                const int* __restrict__ rs,
                                                const int* __restrict__ es)
{
  const int wid  = (blockIdx.x * 256 + threadIdx.x) >> 6;
  const int lane = threadIdx.x & 63;
  if (wid >= NN) return;
  const int beg = rs[wid];
  const int end = rs[wid + 1];
  const int off = lane * 2;

  const unsigned int self = *reinterpret_cast<const unsigned int*>(feat + (size_t)wid * DF + off);
  float ax = b2f(self & 0xffff), ay = b2f(self >> 16);
  int j = beg;
  while (j < end && (j & 3)) {
    const unsigned int u = *reinterpret_cast<const unsigned int*>(feat + (size_t)es[j] * DF + off);
    ax += b2f(u & 0xffff);
    ay += b2f(u >> 16);
    ++j;
  }
  for (; j + 3 < end; j += 4) {
    const int4 e4 = *reinterpret_cast<const int4*>(es + j);
    const unsigned int u0 = *reinterpret_cast<const unsigned int*>(feat + (size_t)e4.x * DF + off);
    const unsigned int u1 = *reinterpret_cast<const unsigned int*>(feat + (size_t)e4.y * DF + off);
    const unsigned int u2 = *reinterpret_cast<const unsigned int*>(feat + (size_t)e4.z * DF + off);
    const unsigned int u3 = *reinterpret_cast<const unsigned int*>(feat + (size_t)e4.w * DF + off);
    ax += b2f(u0 & 0xffff) + b2f(u1 & 0xffff) + b2f(u2 & 0xffff) + b2f(u3 & 0xffff);
    ay += b2f(u0 >> 16)    + b2f(u1 >> 16)    + b2f(u2 >> 16)    + b2f(u3 >> 16);
  }
  for (; j < end; ++j) {
    const unsigned int u = *reinterpret_cast<const unsigned int*>(feat + (size_t)es[j] * DF + off);
    ax += b2f(u & 0xffff);
    ay += b2f(u >> 16);
  }
  const unsigned int o = f2b(ax) | (f2b(ay) << 16);
  *reinterpret_cast<unsigned int*>(outp + (size_t)wid * DF + off) = o;
}

// ======== fused double GEMM: out = relu(relu(A@Wa+ba)@Wb+bb), bf16 MFMA ========
// Wa in VGPRs; Wb rotated in LDS; h bounced through wave-private LDS.
__global__ __launch_bounds__(256) void k_gemm2(const unsigned short* __restrict__ Ab,
                                               const unsigned short* __restrict__ Wta,
                                               const float* __restrict__ ba,
                                               const unsigned short* __restrict__ Wtb,
                                               const float* __restrict__ bb,
                                               unsigned short* __restrict__ outb, int M)
{
  __shared__ unsigned short WbL[128 * 128];     // 32 KB, rotated: [n][(kb+n)&15]
  __shared__ unsigned short hL[4][16 * RT];     // per-wave h staging
  const int tid  = threadIdx.x;
  const int lane = tid & 63;
  const int w    = tid >> 6;
  const int col  = lane & 15;
  const int kq   = lane >> 4;

  // stage Wb rotated (coalesced 16B)
  for (int i = tid; i < 2048; i += 256) {       // i = n*16 + kb
    const int n = i >> 4, kb = i & 15;
    const int kbp = (kb + n) & 15;
    *reinterpret_cast<uint4*>(&WbL[n * 128 + kbp * 8]) =
        *reinterpret_cast<const uint4*>(&Wtb[(size_t)n * 128 + kb * 8]);
  }

  // Wa fragments resident in VGPRs
  bf16x8 wfa[8][4];
#pragma unroll
  for (int nf = 0; nf < 8; ++nf)
#pragma unroll
    for (int s = 0; s < 4; ++s)
      wfa[nf][s] = *reinterpret_cast<const bf16x8*>(
          Wta + (size_t)(nf * 16 + col) * DF + s * 32 + kq * 8);

  __syncthreads();

  unsigned short* hw = &hL[w][0];
  const int rbase = blockIdx.x * 256;

  int m = rbase + w * 16 + col;
  int mld = (m < M) ? m : (M - 1);
  bf16x8 bc[4];
#pragma unroll
  for (int s = 0; s < 4; ++s)
    bc[s] = *reinterpret_cast<const bf16x8*>(Ab + (size_t)mld * DF + s * 32 + kq * 8);

#pragma unroll
  for (int t = 0; t < 4; ++t) {
    bf16x8 bn[4];
    if (t < 3) {
      const int m2 = rbase + (t + 1) * 64 + w * 16 + col;
      const int mld2 = (m2 < M) ? m2 : (M - 1);
#pragma unroll
      for (int s = 0; s < 4; ++s)
        bn[s] = *reinterpret_cast<const bf16x8*>(Ab + (size_t)mld2 * DF + s * 32 + kq * 8);
    }
    // ---- GEMM1 ----
    f32x4 acc[8];
#pragma unroll
    for (int nf = 0; nf < 8; ++nf) acc[nf] = (f32x4){0.f, 0.f, 0.f, 0.f};
#pragma unroll
    for (int s = 0; s < 4; ++s)
#pragma unroll
      for (int nf = 0; nf < 8; ++nf)
        acc[nf] = __builtin_amdgcn_mfma_f32_16x16x32_bf16(wfa[nf][s], bc[s], acc[nf], 0, 0, 0);
    // ---- bias_a + relu -> bf16 -> wave-private LDS ----
#pragma unroll
    for (int nf = 0; nf < 8; ++nf) {
      const float4 bv = *reinterpret_cast<const float4*>(ba + nf * 16 + kq * 4);
      uint2 pk;
      pk.x = f2b(fmaxf(acc[nf][0] + bv.x, 0.f)) | (f2b(fmaxf(acc[nf][1] + bv.y, 0.f)) << 16);
      pk.y = f2b(fmaxf(acc[nf][2] + bv.z, 0.f)) | (f2b(fmaxf(acc[nf][3] + bv.w, 0.f)) << 16);
      *reinterpret_cast<uint2*>(&hw[col * RT + nf * 16 + kq * 4]) = pk;
    }
    asm volatile("s_waitcnt lgkmcnt(0)" ::: "memory");
    __builtin_amdgcn_sched_barrier(0);
    // ---- GEMM2 ----
    f32x4 acc2[8];
#pragma unroll
    for (int nf = 0; nf < 8; ++nf) acc2[nf] = (f32x4){0.f, 0.f, 0.f, 0.f};
#pragma unroll
    for (int s = 0; s < 4; ++s) {
      const bf16x8 hb = *reinterpret_cast<const bf16x8*>(&hw[col * RT + s * 32 + kq * 8]);
#pragma unroll
      for (int nf = 0; nf < 8; ++nf) {
        const int kbp = (s * 4 + kq + col) & 15;    // (kb + n)&15, n = nf*16+col
        const bf16x8 wb = *reinterpret_cast<const bf16x8*>(&WbL[(nf * 16 + col) * 128 + kbp * 8]);
        acc2[nf] = __builtin_amdgcn_mfma_f32_16x16x32_bf16(wb, hb, acc2[nf], 0, 0, 0);
      }
    }
    if (m < M) {
#pragma unroll
      for (int nf = 0; nf < 8; ++nf) {
        const float4 bv = *reinterpret_cast<const float4*>(bb + nf * 16 + kq * 4);
        ushort4 p;
        p.x = (unsigned short)f2b(fmaxf(acc2[nf][0] + bv.x, 0.f));
        p.y = (unsigned short)f2b(fmaxf(acc2[nf][1] + bv.y, 0.f));
        p.z = (unsigned short)f2b(fmaxf(acc2[nf][2] + bv.z, 0.f));
        p.w = (unsigned short)f2b(fmaxf(acc2[nf][3] + bv.w, 0.f));
        *reinterpret_cast<ushort4*>(outb + (size_t)m * DF + nf * 16 + kq * 4) = p;
      }
    }
#pragma unroll
    for (int s = 0; s < 4; ++s) bc[s] = bn[s];
    m = rbase + (t + 1) * 64 + w * 16 + col;
    mld = (m < M) ? m : (M - 1);
  }
}

// ======== segment-mean pooling: one wave per 32 contiguous nodes ========
__global__ __launch_bounds__(256) void k_pool(const unsigned short* __restrict__ h,
                                              const int* __restrict__ batch,
                                              float* __restrict__ sums,
                                              int* __restrict__ cnts)
{
  const int wv   = (blockIdx.x * 256 + threadIdx.x) >> 6;
  const int lane = threadIdx.x & 63;
  const int n0 = wv * 32;
  if (n0 >= NN) return;
  const int n1 = min(n0 + 32, NN);
  const int off = lane * 2;

  const int gfirst = batch[n0];
  const int glast  = batch[n1 - 1];
  float ax = 0.f, ay = 0.f;

  if (gfirst == glast) {
#pragma unroll 4
    for (int i = n0; i < n1; ++i) {
      const unsigned int u = *reinterpret_cast<const unsigned int*>(h + (size_t)i * DF + off);
      ax += b2f(u & 0xffff);
      ay += b2f(u >> 16);
    }
    atomAddF(&sums[gfirst * DF + off],     ax);
    atomAddF(&sums[gfirst * DF + off + 1], ay);
    if (lane == 0) atomicAdd(&cnts[gfirst], n1 - n0);
  } else {
    int g = gfirst, cnt = 0;
    for (int i = n0; i < n1; ++i) {
      const int gi = batch[i];
      if (gi != g) {
        atomAddF(&sums[g * DF + off],     ax);
        atomAddF(&sums[g * DF + off + 1], ay);
        if (lane == 0) atomicAdd(&cnts[g], cnt);
        ax = 0.f; ay = 0.f; cnt = 0; g = gi;
      }
      const unsigned int u = *reinterpret_cast<const unsigned int*>(h + (size_t)i * DF + off);
      ax += b2f(u & 0xffff);
      ay += b2f(u >> 16);
      ++cnt;
    }
    atomAddF(&sums[g * DF + off],     ax);
    atomAddF(&sums[g * DF + off + 1], ay);
    if (lane == 0) atomicAdd(&cnts[g], cnt);
  }
}

// ======== head ========
__global__ __launch_bounds__(256) void k_head(const float* __restrict__ sums,
                                              const int* __restrict__ cnts,
                                              const float* __restrict__ Wfc,
                                              const float* __restrict__ bfc,
                                              float* __restrict__ out)
{
  for (int o = threadIdx.x; o < NG * NC; o += 256) {
    const int g = o / NC, c = o % NC;
    const float inv = 1.f / fmaxf((float)cnts[g], 1.f);
    float z = bfc[c];
    for (int k = 0; k < DF; ++k)
      z = fmaf(sums[g * DF + k] * inv, Wfc[k * NC + c], z);
    out[o] = 1.f / (1.f + expf(-z));
  }
}

extern "C" void kernel_launch(void* const* d_in, const int* in_sizes, int n_in,
                              void* d_out, int out_size, void* d_ws, size_t ws_size,
                              hipStream_t stream)
{
  const float* x   = (const float*)d_in[0];
  const int*   ei  = (const int*)d_in[1];
  const int* batch = (const int*)d_in[2];
  const float* W1a = (const float*)d_in[3];
  const float* b1a = (const float*)d_in[4];
  const float* W1b = (const float*)d_in[5];
  const float* b1b = (const float*)d_in[6];
  const float* W2a = (const float*)d_in[7];
  const float* b2a = (const float*)d_in[8];
  const float* W2b = (const float*)d_in[9];
  const float* b2b = (const float*)d_in[10];
  const float* Wfc = (const float*)d_in[11];
  const float* bfc = (const float*)d_in[12];
  float* out = (float*)d_out;

  const int* src = ei;           // edge_index[0]
  const int* dst = ei + NE;      // edge_index[1]

  // ws layout: [ushort] xb | A | H | Wt(4)   then [int/float] sums | cnts | cnt_b | base_b | rs | pad | es | arena
  unsigned short* xb = (unsigned short*)d_ws;
  unsigned short* A  = xb + (size_t)NN * DF;
  unsigned short* H  = A + (size_t)NN * DF;
  unsigned short* Wt = H + (size_t)NN * DF;
  float* sums  = (float*)(Wt + (size_t)4 * DF * DF);
  int*   cnts  = (int*)(sums + NG * DF);      // 64
  int*   cnt_b = cnts + 64;                   // 128
  int*   base_b= cnt_b + 128;                 // 128
  int*   rs    = base_b + 128;                // NN+1 (+3 pad)
  int*   es    = rs + (NN + 4);               // NE  (16B aligned)
  unsigned int* arena = (unsigned int*)(es + NE);  // 98*ACAP

  unsigned short* Wt1a = Wt;
  unsigned short* Wt1b = Wt + DF * DF;
  unsigned short* Wt2a = Wt + 2 * DF * DF;
  unsigned short* Wt2b = Wt + 3 * DF * DF;

  const int gemm_grid   = (NN + 255) / 256;        // 196
  const int gather_grid = (NN * 64 + 255) / 256;   // 12500
  const int pool_grid   = ((NN + 31) / 32 + 3) / 4;  // 391

  // ---- prep ----
  k_cast<<<(NN * DF / 4 + 255) / 256, 256, 0, stream>>>(x, xb);
  k_prepw<<<32, 256, 0, stream>>>(W1a, W1b, W2a, W2b, Wt);
  hipMemsetAsync(sums, 0, (size_t)(NG * DF + 64 + 128) * sizeof(float), stream);  // sums+cnts+cnt_b
  k_part<<<PART_GRID, 256, 0, stream>>>(src, dst, cnt_b, arena);
  k_bscan<<<1, 128, 0, stream>>>(cnt_b, base_b, rs);
  k_fine<<<NBK, 256, 0, stream>>>(arena, cnt_b, base_b, rs, es);

  // ---- conv1 ----
  k_gather<<<gather_grid, 256, 0, stream>>>(xb, A, rs, es);
  k_gemm2<<<gemm_grid, 256, 0, stream>>>(A, Wt1a, b1a, Wt1b, b1b, A, NN);

  // ---- conv2 ----
  k_gather<<<gather_grid, 256, 0, stream>>>(A, H, rs, es);
  k_gemm2<<<gemm_grid, 256, 0, stream>>>(H, Wt2a, b2a, Wt2b, b2b, H, NN);

  // ---- pool + head ----
  k_pool<<<pool_grid, 256, 0, stream>>>(H, batch, sums, cnts);
  k_head<<<1, 256, 0, stream>>>(sums, cnts, Wfc, bfc, out);
}